// Round 3
// baseline (438.838 us; speedup 1.0000x reference)
//
#include <hip/hip_runtime.h>

#define N_IMG 64
#define C_CH  512
#define HW    1024
#define G_GRP 8
#define L_CH  64

// workspace layout (floats):
//   S       [8][64][64]  @ 0       (32768)   zeroed
//   chansum [512]        @ 32768             zeroed
//   v0f     [512]        @ 33280
//   w2      [512]        @ 33792
//   b2      [512]        @ 34304
//   dot0    [8]          @ 34816
// total ~140 KB of d_ws

// ---------------------------------------------------------------------------
// Kernel 1: per-(group, image) Gram partial S += A·Aᵀ  (A = 64ch × 1024hw)
// plus per-channel sums. 512 blocks × 256 threads. fp32 VALU (no fp32 MFMA).
// LDS: 17.4 KB.
// ---------------------------------------------------------------------------
__global__ __launch_bounds__(256) void cov_kernel(const float* __restrict__ x,
                                                  float* __restrict__ S,
                                                  float* __restrict__ chansum) {
  const int g = blockIdx.x & 7;
  const int n = blockIdx.x >> 3;
  // k-major tile: As[kk][row], row-dim padded 64->68 (keeps float4 alignment,
  // banks -> <=2-way conflicts on row reads, free per m136)
  __shared__ __align__(16) float As[64][68];
  const int t  = threadIdx.x;
  const int ti = t >> 4;          // 0..15
  const int tj = t & 15;          // 0..15
  float acc[4][4];
#pragma unroll
  for (int r = 0; r < 4; r++)
#pragma unroll
    for (int s = 0; s < 4; s++) acc[r][s] = 0.f;
  float rsum = 0.f;

  const float* base = x + ((size_t)(n * C_CH + g * L_CH)) * HW;
  const int kk4 = tj << 2;

  for (int k0 = 0; k0 < HW; k0 += 64) {
    // load 64 rows x 64 cols, transposed into LDS
#pragma unroll
    for (int s = 0; s < 4; s++) {
      const int row = ti + 16 * s;
      const float4 v = *(const float4*)(base + (size_t)row * HW + k0 + kk4);
      As[kk4 + 0][row] = v.x;
      As[kk4 + 1][row] = v.y;
      As[kk4 + 2][row] = v.z;
      As[kk4 + 3][row] = v.w;
    }
    __syncthreads();
#pragma unroll 8
    for (int kk = 0; kk < 64; kk++) {
      const float4 a = *(const float4*)&As[kk][4 * ti];
      const float4 b = *(const float4*)&As[kk][4 * tj];
      acc[0][0] += a.x * b.x; acc[0][1] += a.x * b.y; acc[0][2] += a.x * b.z; acc[0][3] += a.x * b.w;
      acc[1][0] += a.y * b.x; acc[1][1] += a.y * b.y; acc[1][2] += a.y * b.z; acc[1][3] += a.y * b.w;
      acc[2][0] += a.z * b.x; acc[2][1] += a.z * b.y; acc[2][2] += a.z * b.z; acc[2][3] += a.z * b.w;
      acc[3][0] += a.w * b.x; acc[3][1] += a.w * b.y; acc[3][2] += a.w * b.z; acc[3][3] += a.w * b.w;
    }
    if (t < 64) {  // per-channel sums (for the mean), one 64-col slice per chunk
      float s2 = 0.f;
#pragma unroll 8
      for (int kk = 0; kk < 64; kk++) s2 += As[kk][t];
      rsum += s2;
    }
    __syncthreads();
  }

  float* Sg = S + g * 4096;
#pragma unroll
  for (int r = 0; r < 4; r++)
#pragma unroll
    for (int s = 0; s < 4; s++)
      atomicAdd(&Sg[(4 * ti + r) * 64 + (4 * tj + s)], acc[r][s]);
  if (t < 64) atomicAdd(&chansum[g * 64 + t], rsum);
}

// ---------------------------------------------------------------------------
// Kernel 2: per-group top eigenpair of cov = S/M - mu muT + eps I.
// Spectrum near-degenerate (MP law: lam2/lam1 ~ 0.99) -> 12 in-place matrix
// squarings of (C - sigma*I), trace-normalized, fp32 LDS; fp64 Rayleigh.
// 8 blocks x 256 threads. LDS ~52 KB (< 64 KB static limit).
// ---------------------------------------------------------------------------
__global__ __launch_bounds__(256) void eigen_kernel(
    const float* __restrict__ S, const float* __restrict__ chansum,
    const float* __restrict__ weight, const float* __restrict__ bias,
    float* __restrict__ v0f, float* __restrict__ w2,
    float* __restrict__ b2, float* __restrict__ dot0) {
  const int g = blockIdx.x;
  __shared__ __align__(16) float Bf[64][68];   // 17408 B
  __shared__ double Cd[64][65];                // 33280 B
  __shared__ double vv[64], uu[64];            // 1024 B
  __shared__ double sred;
  __shared__ float strace;
  __shared__ float sigma_s;
  __shared__ int jstar;
  const int t = threadIdx.x;
  const double Minv = 1.0 / 65536.0;

  // build cov in fp64
  for (int idx = t; idx < 4096; idx += 256) {
    const int i = idx >> 6, j = idx & 63;
    const double mui = (double)chansum[g * 64 + i] * Minv;
    const double muj = (double)chansum[g * 64 + j] * Minv;
    Cd[i][j] = (double)S[g * 4096 + idx] * Minv - mui * muj + (i == j ? 1e-4 : 0.0);
  }
  __syncthreads();
  if (t == 0) {
    double mind = 1e300;
    for (int i = 0; i < 64; i++) mind = fmin(mind, Cd[i][i]);
    sigma_s = (float)(0.49 * fmax(mind, 0.0));  // PSD-safe shift (sigma < lammin)
  }
  __syncthreads();
  const float sg = sigma_s;
  for (int idx = t; idx < 4096; idx += 256) {
    const int i = idx >> 6, j = idx & 63;
    Bf[i][j] = (float)Cd[i][j] - (i == j ? sg : 0.f);
  }
  __syncthreads();

  // in-place squaring: thread t owns row i = t&63, 16-col slab j0 = (t>>6)*16
  const int i  = t & 63;
  const int j0 = (t >> 6) << 4;   // wave-uniform (lanes 0..63 share t>>6)
  for (int it = 0; it < 12; it++) {
    if (t == 0) {
      float tr = 0.f;
      for (int d = 0; d < 64; d++) tr += Bf[d][d];
      strace = 1.f / tr;
    }
    __syncthreads();
    const float sc = strace;
    float r[16];
#pragma unroll
    for (int q = 0; q < 16; q++) r[q] = 0.f;
#pragma unroll 8
    for (int k = 0; k < 64; k++) {
      const float bik = Bf[k][i];                           // 2-way banks: free
      const float4 b0 = *(const float4*)&Bf[k][j0 + 0];     // wave-broadcast
      const float4 b1 = *(const float4*)&Bf[k][j0 + 4];
      const float4 b2v = *(const float4*)&Bf[k][j0 + 8];
      const float4 b3 = *(const float4*)&Bf[k][j0 + 12];
      r[0] += bik * b0.x;  r[1] += bik * b0.y;  r[2] += bik * b0.z;  r[3] += bik * b0.w;
      r[4] += bik * b1.x;  r[5] += bik * b1.y;  r[6] += bik * b1.z;  r[7] += bik * b1.w;
      r[8] += bik * b2v.x; r[9] += bik * b2v.y; r[10] += bik * b2v.z; r[11] += bik * b2v.w;
      r[12] += bik * b3.x; r[13] += bik * b3.y; r[14] += bik * b3.z; r[15] += bik * b3.w;
    }
    const float scl = sc * sc;
    __syncthreads();  // all reads of Bf complete before in-place write
#pragma unroll
    for (int q = 0; q < 4; q++) {
      float4 w4;
      w4.x = r[4 * q + 0] * scl; w4.y = r[4 * q + 1] * scl;
      w4.z = r[4 * q + 2] * scl; w4.w = r[4 * q + 3] * scl;
      *(float4*)&Bf[i][j0 + 4 * q] = w4;
    }
    __syncthreads();
  }

  // dominant eigenvector: column of max diagonal (diag = c*v0[j]^2)
  if (t == 0) {
    float best = -1.f; int bj = 0;
    for (int j = 0; j < 64; j++) {
      const float d = Bf[j][j];
      if (d > best) { best = d; bj = j; }
    }
    jstar = bj;
  }
  __syncthreads();
  if (t < 64) vv[t] = (double)Bf[t][jstar];
  __syncthreads();

  // fp64: normalize + 3 power steps (cleans fp32 round-off from last squaring)
  for (int pi = 0; pi < 3; pi++) {
    if (t < 64) {
      double s = 0.0;
      for (int k = 0; k < 64; k++) s += Cd[t][k] * vv[k];
      uu[t] = s;
    }
    __syncthreads();
    if (t == 0) {
      double nn = 0.0;
      for (int k = 0; k < 64; k++) nn += uu[k] * uu[k];
      sred = 1.0 / sqrt(nn);
    }
    __syncthreads();
    if (t < 64) vv[t] = uu[t] * sred;
    __syncthreads();
  }
  // Rayleigh quotient (2nd-order accurate in eigvec error)
  if (t < 64) {
    double s = 0.0;
    for (int k = 0; k < 64; k++) s += Cd[t][k] * vv[k];
    uu[t] = s;
  }
  __syncthreads();
  if (t == 0) {
    double lam = 0.0;
    for (int k = 0; k < 64; k++) lam += vv[k] * uu[k];
    sred = 1.0 / sqrt(lam);  // rsqrt(e0)
  }
  __syncthreads();

  if (t < 64) {
    const int c = g * 64 + t;
    v0f[c] = (float)vv[t];
    w2[c]  = (float)((double)weight[c] * sred * vv[t]);
    b2[c]  = bias[c];
  }
  if (t == 0) {
    double d = 0.0;
    for (int k = 0; k < 64; k++) d += vv[k] * ((double)chansum[g * 64 + k] * Minv);
    dot0[g] = (float)d;
  }
}

// ---------------------------------------------------------------------------
// Kernel 3: out = w2[c] * (v0 . (x_col - mu)) + b2[c].
// 512 blocks (g,n) x 256 threads, float4 (16 B/lane) both ways. HBM-bound.
// ---------------------------------------------------------------------------
__global__ __launch_bounds__(256) void apply_kernel(
    const float* __restrict__ x, const float* __restrict__ v0f,
    const float* __restrict__ w2, const float* __restrict__ b2,
    const float* __restrict__ dot0, float* __restrict__ out) {
  const int g = blockIdx.x & 7;
  const int n = blockIdx.x >> 3;
  __shared__ float vs[64], wsh[64], bsh[64];
  const int t = threadIdx.x;
  if (t < 64) {
    vs[t]  = v0f[g * 64 + t];
    wsh[t] = w2[g * 64 + t];
    bsh[t] = b2[g * 64 + t];
  }
  __syncthreads();
  const size_t boff = ((size_t)(n * C_CH + g * L_CH)) * HW + 4 * t;
  const float* base = x + boff;
  float4 p = {0.f, 0.f, 0.f, 0.f};
#pragma unroll 8
  for (int l = 0; l < 64; l++) {
    const float4 xv = *(const float4*)(base + (size_t)l * HW);
    const float vl = vs[l];
    p.x += vl * xv.x; p.y += vl * xv.y; p.z += vl * xv.z; p.w += vl * xv.w;
  }
  const float d0 = dot0[g];
  p.x -= d0; p.y -= d0; p.z -= d0; p.w -= d0;
  float* obase = out + boff;
#pragma unroll 8
  for (int l = 0; l < 64; l++) {
    const float wl = wsh[l], bl = bsh[l];
    float4 o;
    o.x = wl * p.x + bl; o.y = wl * p.y + bl; o.z = wl * p.z + bl; o.w = wl * p.w + bl;
    *(float4*)(obase + (size_t)l * HW) = o;
  }
}

extern "C" void kernel_launch(void* const* d_in, const int* in_sizes, int n_in,
                              void* d_out, int out_size, void* d_ws, size_t ws_size,
                              hipStream_t stream) {
  const float* x      = (const float*)d_in[0];
  const float* weight = (const float*)d_in[1];
  const float* bias   = (const float*)d_in[2];
  float* out = (float*)d_out;
  float* ws  = (float*)d_ws;

  float* S       = ws;            // 32768
  float* chansum = ws + 32768;    // 512
  float* v0f     = ws + 33280;    // 512
  float* w2      = ws + 33792;    // 512
  float* b2      = ws + 34304;    // 512
  float* dot0    = ws + 34816;    // 8

  // accumulators must be zero each call (ws is re-poisoned to 0xAA)
  hipMemsetAsync(d_ws, 0, (32768 + 512) * sizeof(float), stream);

  cov_kernel<<<dim3(512), dim3(256), 0, stream>>>(x, S, chansum);
  eigen_kernel<<<dim3(8), dim3(256), 0, stream>>>(S, chansum, weight, bias,
                                                  v0f, w2, b2, dot0);
  apply_kernel<<<dim3(512), dim3(256), 0, stream>>>(x, v0f, w2, b2, dot0, out);
}

// Round 4
// 329.326 us; speedup vs baseline: 1.3325x; 1.3325x over previous
//
#include <hip/hip_runtime.h>

#define HW    1024
#define C_CH  512

// ws layout (floats): S[8][4096] @0 (zeroed), chansum[512] @32768 (zeroed),
//                     v0f[512] @33280, w2[512] @33792, b2[512] @34304
// d_out doubles as scratch for cov partial tiles: Spart[2048][4096] (33.5 MB),
// consumed by reduce_kernel BEFORE apply_kernel overwrites d_out.

// ---------------------------------------------------------------------------
// K1: per-(g,n,ks) Gram partial of a 64ch x 256hw slab. 2048 blocks x 256 thr.
// LDS 16 KB, XOR-swizzled k-major tile: logical As[kk][row] lives at word
//   kk*64 + 4*((row>>2)^(kk>>2)) + (row&3)
// -> staging scalar writes hit 64 distinct words (2-way banks, free);
// -> compute float4 reads stay 16B-aligned (per-kk XOR permutes 16B blocks).
// ---------------------------------------------------------------------------
__global__ __launch_bounds__(256, 8) void cov_kernel(const float* __restrict__ x,
                                                     float* __restrict__ Spart,
                                                     float* __restrict__ chansum) {
  const int ks = blockIdx.x & 3;
  const int n  = (blockIdx.x >> 2) & 63;
  const int g  = blockIdx.x >> 8;
  __shared__ __align__(16) float As[4096];
  const int t  = threadIdx.x;
  const int ti = t >> 4;   // 0..15
  const int tj = t & 15;   // 0..15
  float acc[4][4];
#pragma unroll
  for (int r = 0; r < 4; r++)
#pragma unroll
    for (int s = 0; s < 4; s++) acc[r][s] = 0.f;
  float rsum = 0.f;

  const float* base = x + ((size_t)(n * C_CH + g * 64)) * HW;
  const int rlo = t >> 4;   // staging row low bits
  const int cc  = t & 15;   // staging col4 (= kk>>2)

  for (int chunk = 0; chunk < 4; chunk++) {
    const int k0 = ks * 256 + chunk * 64;
#pragma unroll
    for (int s = 0; s < 4; s++) {
      const int row = 16 * s + rlo;
      const float4 v = *(const float4*)(base + (size_t)row * HW + k0 + 4 * cc);
      const int w0 = 4 * ((row >> 2) ^ cc) + (row & 3);
      As[(4 * cc + 0) * 64 + w0] = v.x;
      As[(4 * cc + 1) * 64 + w0] = v.y;
      As[(4 * cc + 2) * 64 + w0] = v.z;
      As[(4 * cc + 3) * 64 + w0] = v.w;
    }
    __syncthreads();
#pragma unroll 16
    for (int kk = 0; kk < 64; kk++) {
      const int kq = kk >> 2;
      const float4 a = *(const float4*)&As[kk * 64 + 4 * (ti ^ kq)];
      const float4 b = *(const float4*)&As[kk * 64 + 4 * (tj ^ kq)];
      acc[0][0] += a.x * b.x; acc[0][1] += a.x * b.y; acc[0][2] += a.x * b.z; acc[0][3] += a.x * b.w;
      acc[1][0] += a.y * b.x; acc[1][1] += a.y * b.y; acc[1][2] += a.y * b.z; acc[1][3] += a.y * b.w;
      acc[2][0] += a.z * b.x; acc[2][1] += a.z * b.y; acc[2][2] += a.z * b.z; acc[2][3] += a.z * b.w;
      acc[3][0] += a.w * b.x; acc[3][1] += a.w * b.y; acc[3][2] += a.w * b.z; acc[3][3] += a.w * b.w;
    }
    if (t < 64) {  // per-channel sum of this chunk (column t of the tile)
      float s2 = 0.f;
#pragma unroll 16
      for (int kk = 0; kk < 64; kk++)
        s2 += As[kk * 64 + 4 * ((t >> 2) ^ (kk >> 2)) + (t & 3)];
      rsum += s2;
    }
    __syncthreads();
  }

  // non-atomic partial tile -> d_out scratch
  float* P = Spart + ((size_t)(g * 256 + n * 4 + ks)) * 4096;
#pragma unroll
  for (int r = 0; r < 4; r++) {
    float4 w4;
    w4.x = acc[r][0]; w4.y = acc[r][1]; w4.z = acc[r][2]; w4.w = acc[r][3];
    *(float4*)&P[(4 * ti + r) * 64 + 4 * tj] = w4;
  }
  if (t < 64) atomicAdd(&chansum[g * 64 + t], rsum);
}

// ---------------------------------------------------------------------------
// K2: fold 256 partial tiles per group into S. 512 blocks x 256 thr.
// Each thread sums a 64-partial quarter of one (g,entry); 4 atomics/address.
// ---------------------------------------------------------------------------
__global__ __launch_bounds__(256) void reduce_kernel(const float* __restrict__ Spart,
                                                     float* __restrict__ S) {
  const int q   = blockIdx.x >> 7;                       // 0..3
  const int idx = (blockIdx.x & 127) * 256 + threadIdx.x; // 0..32767
  const int g   = idx >> 12;
  const int e   = idx & 4095;
  const float* P = Spart + ((size_t)(g * 256 + q * 64)) * 4096 + e;
  float s = 0.f;
#pragma unroll 8
  for (int p = 0; p < 64; p++) s += P[(size_t)p * 4096];
  atomicAdd(&S[idx], s);
}

// ---------------------------------------------------------------------------
// K3: per-group top eigenpair of cov = S/M - mu muT + eps I.
// 12 in-place trace-normalized squarings of (C - sigma I) in fp32 LDS
// (4x4 register tiles, conflict-free), fp64 power polish + Rayleigh.
// 8 blocks x 256 threads. LDS ~52 KB.
// ---------------------------------------------------------------------------
__global__ __launch_bounds__(256) void eigen_kernel(
    const float* __restrict__ S, const float* __restrict__ chansum,
    const float* __restrict__ weight, const float* __restrict__ bias,
    float* __restrict__ v0f, float* __restrict__ w2, float* __restrict__ b2) {
  const int g = blockIdx.x;
  __shared__ __align__(16) float Bf[64 * 68];  // 17408 B, stride 68
  __shared__ double Cd[64][65];                // 33280 B
  __shared__ double vv[64], uu[64];
  __shared__ double dred;
  __shared__ float f32red;
  __shared__ int ired;
  const int t  = threadIdx.x;
  const int ti = t >> 4, tj = t & 15;
  const double Minv = 1.0 / 65536.0;

  for (int idx = t; idx < 4096; idx += 256) {
    const int i = idx >> 6, j = idx & 63;
    const double mui = (double)chansum[g * 64 + i] * Minv;
    const double muj = (double)chansum[g * 64 + j] * Minv;
    Cd[i][j] = (double)S[g * 4096 + idx] * Minv - mui * muj + (i == j ? 1e-4 : 0.0);
  }
  __syncthreads();
  if (t < 64) {  // PSD-safe shift: sigma = 0.49 * min(diag) <= 0.49*lam_min... < lam1/2
    double d = Cd[t][t];
#pragma unroll
    for (int off = 32; off; off >>= 1) d = fmin(d, __shfl_down(d, off));
    if (t == 0) f32red = (float)(0.49 * fmax(d, 0.0));
  }
  __syncthreads();
  const float sg = f32red;
  for (int idx = t; idx < 4096; idx += 256) {
    const int i = idx >> 6, j = idx & 63;
    Bf[i * 68 + j] = (float)Cd[i][j] - (i == j ? sg : 0.f);
  }
  __syncthreads();

  for (int it = 0; it < 12; it++) {
    if (t < 64) {
      float tr = Bf[t * 68 + t];
#pragma unroll
      for (int off = 32; off; off >>= 1) tr += __shfl_down(tr, off);
      if (t == 0) f32red = 1.f / tr;
    }
    __syncthreads();
    const float sc = f32red, scl = sc * sc;
    float acc[4][4];
#pragma unroll
    for (int r = 0; r < 4; r++)
#pragma unroll
      for (int s = 0; s < 4; s++) acc[r][s] = 0.f;
#pragma unroll 16
    for (int kk = 0; kk < 64; kk++) {  // B symmetric: rows == cols
      const float4 a = *(const float4*)&Bf[kk * 68 + 4 * ti];
      const float4 b = *(const float4*)&Bf[kk * 68 + 4 * tj];
      acc[0][0] += a.x * b.x; acc[0][1] += a.x * b.y; acc[0][2] += a.x * b.z; acc[0][3] += a.x * b.w;
      acc[1][0] += a.y * b.x; acc[1][1] += a.y * b.y; acc[1][2] += a.y * b.z; acc[1][3] += a.y * b.w;
      acc[2][0] += a.z * b.x; acc[2][1] += a.z * b.y; acc[2][2] += a.z * b.z; acc[2][3] += a.z * b.w;
      acc[3][0] += a.w * b.x; acc[3][1] += a.w * b.y; acc[3][2] += a.w * b.z; acc[3][3] += a.w * b.w;
    }
    __syncthreads();
#pragma unroll
    for (int r = 0; r < 4; r++) {
      float4 w4;
      w4.x = acc[r][0] * scl; w4.y = acc[r][1] * scl;
      w4.z = acc[r][2] * scl; w4.w = acc[r][3] * scl;
      *(float4*)&Bf[(4 * ti + r) * 68 + 4 * tj] = w4;
    }
    __syncthreads();
  }

  // dominant eigvec ~ column jstar of B^(2^12), jstar = argmax diag
  if (t < 64) {
    float d = Bf[t * 68 + t];
    int bj = t;
#pragma unroll
    for (int off = 32; off; off >>= 1) {
      const float od = __shfl_down(d, off);
      const int   oj = __shfl_down(bj, off);
      if (od > d) { d = od; bj = oj; }
    }
    if (t == 0) ired = bj;
  }
  __syncthreads();
  const int jstar = ired;
  if (t < 64) vv[t] = (double)Bf[t * 68 + jstar];
  __syncthreads();

  for (int pi = 0; pi < 3; pi++) {  // fp64 power polish
    if (t < 64) {
      double s = 0.0;
      for (int k = 0; k < 64; k++) s += Cd[t][k] * vv[k];
      uu[t] = s;
    }
    __syncthreads();
    if (t < 64) {
      double q = uu[t] * uu[t];
#pragma unroll
      for (int off = 32; off; off >>= 1) q += __shfl_down(q, off);
      if (t == 0) dred = 1.0 / sqrt(q);
    }
    __syncthreads();
    if (t < 64) vv[t] = uu[t] * dred;
    __syncthreads();
  }
  if (t < 64) {  // Rayleigh quotient
    double s = 0.0;
    for (int k = 0; k < 64; k++) s += Cd[t][k] * vv[k];
    uu[t] = s;
  }
  __syncthreads();
  if (t < 64) {
    double q = vv[t] * uu[t];
#pragma unroll
    for (int off = 32; off; off >>= 1) q += __shfl_down(q, off);
    if (t == 0) dred = 1.0 / sqrt(q);  // rsqrt(lam1)
  }
  __syncthreads();
  const double rsl = dred;
  double w2v = 0.0;
  if (t < 64) {
    const int c = g * 64 + t;
    v0f[c] = (float)vv[t];
    w2v = (double)weight[c] * rsl * vv[t];
    w2[c] = (float)w2v;
  }
  __syncthreads();
  if (t < 64) {  // d0 = v0 . mu, fold into bias
    double q = vv[t] * ((double)chansum[g * 64 + t] * Minv);
#pragma unroll
    for (int off = 32; off; off >>= 1) q += __shfl_down(q, off);
    if (t == 0) dred = q;
  }
  __syncthreads();
  if (t < 64) {
    const int c = g * 64 + t;
    b2[c] = (float)((double)bias[c] - w2v * dred);
  }
}

// ---------------------------------------------------------------------------
// K4: out[c][col] = w2[c] * (v0 . x[:,col]) + b2[c].  2048 blocks x 256 thr,
// one column/thread, coalesced 256B scalar transactions. HBM-bound.
// ---------------------------------------------------------------------------
__global__ __launch_bounds__(256, 8) void apply_kernel(
    const float* __restrict__ x, const float* __restrict__ v0f,
    const float* __restrict__ w2, const float* __restrict__ b2,
    float* __restrict__ out) {
  const int q = blockIdx.x & 3;
  const int n = (blockIdx.x >> 2) & 63;
  const int g = blockIdx.x >> 8;
  __shared__ float vs[64], wsh[64], bsh[64];
  const int t = threadIdx.x;
  if (t < 64) {
    vs[t]  = v0f[g * 64 + t];
    wsh[t] = w2[g * 64 + t];
    bsh[t] = b2[g * 64 + t];
  }
  __syncthreads();
  const size_t boff = ((size_t)(n * C_CH + g * 64)) * HW + q * 256 + t;
  const float* base = x + boff;
  float p = 0.f;
#pragma unroll 8
  for (int l = 0; l < 64; l++) p += vs[l] * base[(size_t)l * HW];
  float* ob = out + boff;
#pragma unroll 8
  for (int l = 0; l < 64; l++) ob[(size_t)l * HW] = wsh[l] * p + bsh[l];
}

extern "C" void kernel_launch(void* const* d_in, const int* in_sizes, int n_in,
                              void* d_out, int out_size, void* d_ws, size_t ws_size,
                              hipStream_t stream) {
  const float* x      = (const float*)d_in[0];
  const float* weight = (const float*)d_in[1];
  const float* bias   = (const float*)d_in[2];
  float* out = (float*)d_out;
  float* ws  = (float*)d_ws;

  float* S       = ws;            // 32768
  float* chansum = ws + 32768;    // 512
  float* v0f     = ws + 33280;    // 512
  float* w2      = ws + 33792;    // 512
  float* b2      = ws + 34304;    // 512
  float* Spart   = out;           // d_out as scratch: 2048*4096 floats (33.5 MB)

  hipMemsetAsync(d_ws, 0, (32768 + 512) * sizeof(float), stream);

  cov_kernel<<<dim3(2048), dim3(256), 0, stream>>>(x, Spart, chansum);
  reduce_kernel<<<dim3(512), dim3(256), 0, stream>>>(Spart, S);
  eigen_kernel<<<dim3(8), dim3(256), 0, stream>>>(S, chansum, weight, bias,
                                                  v0f, w2, b2);
  apply_kernel<<<dim3(2048), dim3(256), 0, stream>>>(x, v0f, w2, b2, out);
}